// Round 16
// baseline (80.762 us; speedup 1.0000x reference)
//
#include <hip/hip_runtime.h>
#include <hip/hip_fp8.h>

typedef __attribute__((ext_vector_type(4))) int   i32x4;
typedef __attribute__((ext_vector_type(8))) int   i32x8;
typedef __attribute__((ext_vector_type(16))) float f32x16;

// ---------------------------------------------------------------------------
// Fused slice + convert(f32 -> fp8 e4m3 OCP) + mask-zero for BOTH inputs.
__global__ void conv_kernel(const float* __restrict__ im, const int* __restrict__ iml,
                            const float* __restrict__ ss, const int* __restrict__ sl,
                            unsigned char* __restrict__ Ad, unsigned char* __restrict__ Bd)
{
    int bid = blockIdx.x;
    const float* src; const int* len; unsigned char* dst; int rawL, adj;
    if (bid < 8192) { src = im; len = iml; dst = Ad; rawL = 65; adj = -1; }
    else { bid -= 8192; src = ss; len = sl; dst = Bd; rawL = 67; adj = -3; }
    int m = bid;
    int c = threadIdx.x << 2;
    int b = m >> 6;
    int i = m & 63;
    int lim = len[b] + adj;
    float4 v;
    if (i < lim) {
        v = *(const float4*)(src + ((size_t)(b * rawL + 1 + i) << 10) + c);
    } else {
        v = make_float4(0.f, 0.f, 0.f, 0.f);
    }
    uchar4 o;
    o.x = __hip_cvt_float_to_fp8(v.x, __HIP_SATFINITE, __HIP_E4M3);
    o.y = __hip_cvt_float_to_fp8(v.y, __HIP_SATFINITE, __HIP_E4M3);
    o.z = __hip_cvt_float_to_fp8(v.z, __HIP_SATFINITE, __HIP_E4M3);
    o.w = __hip_cvt_float_to_fp8(v.w, __HIP_SATFINITE, __HIP_E4M3);
    *(uchar4*)(dst + ((size_t)m << 10) + c) = o;
}

// ---------------------------------------------------------------------------
__device__ __forceinline__ void gload_lds16(const void* g, void* l) {
    __builtin_amdgcn_global_load_lds((const __attribute__((address_space(1))) void*)g,
                                     (__attribute__((address_space(3))) void*)l,
                                     16, 0, 0);
}

// Read a 32-byte fp8 fragment as two XOR-swizzled b128 granules.
__device__ __forceinline__ i32x8 rd32(const char* base, int o0) {
    i32x4 a = *(const i32x4*)(base + o0);
    i32x4 b = *(const i32x4*)(base + (o0 ^ 16));
    return __builtin_shufflevector(a, b, 0, 1, 2, 3, 4, 5, 6, 7);
}

// 256x256 tile, BK=64 (fp8: 64B rows), 8 waves (2M x 4N), per-wave 128x64.
// RING-4 LDS + register-double-buffered fragments (r13/r15-verified 72 us).
// NEW (r16): sched_group_barrier interleave {6 DS_READ, 2 MFMA}x4 inside the
// body. r13 removed all DATA deps between reads (tile kt+1) and MFMAs (tile
// kt); SGB now removes the ISSUE-order serialization (in-order wave issue
// meant 24 reads had to issue before the first MFMA; with 8 waves the LDS
// queue jammed and MFMAs stalled behind it -> both pipes <50% busy).
// MFMA: mfma_scale_f32_32x32x64_f8f6f4, e4m3, scale=1 (E8M0 127).
// C/D (r10-verified): col=lane&31, row=(reg&3)+8*(reg>>2)+4*(lane>>5).
__global__ void __launch_bounds__(512) gemm_aggr_kernel(const unsigned char* __restrict__ A,
                                                        const unsigned char* __restrict__ B,
                                                        float* __restrict__ aggr)
{
    __shared__ __align__(16) char As[4][16384];   // 256 rows x 64 B per slot
    __shared__ __align__(16) char Bs[4][16384];

    const int tid  = threadIdx.x;
    const int lane = tid & 63;
    const int wid  = tid >> 6;        // 0..7
    const int wr   = wid >> 2;        // 0..1 : 128-row half of BM=256
    const int wc   = wid & 3;         // 0..3 : 64-col quarter of BN=256
    const int tm   = blockIdx.y;      // 0..31
    const int tn   = blockIdx.x;      // 0..31

    const int r31 = lane & 31;
    const int g2  = lane >> 5;        // 0..1

    // Staging: round = 128 rows x 64 B = 8 KB = 512 thr x 16 B; 2 rounds each.
    // LDS dest linear; global source granule pre-swizzled (both-sides XOR).
    const int srow   = tid >> 2;                  // 0..127
    const int schunk = (tid & 3) ^ ((srow >> 1) & 3);
    const unsigned char* gA_t = A + ((size_t)(tm * 256 + srow) << 10) + schunk * 16;
    const unsigned char* gB_t = B + ((size_t)(tn * 256 + srow) << 10) + schunk * 16;

#define STAGE_A(kt, r) gload_lds16(gA_t + (((size_t)(r) * 128) << 10) + (kt) * 64, \
                                   As[(kt) & 3] + (r) * 8192 + tid * 16)
#define STAGE_B(kt, r) gload_lds16(gB_t + (((size_t)(r) * 128) << 10) + (kt) * 64, \
                                   Bs[(kt) & 3] + (r) * 8192 + tid * 16)

    f32x16 acc[4][2];   // [32-row block mi][32-col block ni]
#pragma unroll
    for (int mi = 0; mi < 4; ++mi)
#pragma unroll
        for (int ni = 0; ni < 2; ++ni)
#pragma unroll
            for (int r = 0; r < 16; ++r)
                acc[mi][ni][r] = 0.f;

    // o0: lane's first granule position (data granule 2*g2, key (r31>>1)&3).
    const int o0 = ((g2 * 2) ^ ((r31 >> 1) & 3)) * 16;
    const int aRow = (wr * 128 + r31) * 64;   // + mi*32*64
    const int bRow = (wc * 64 + r31) * 64;    // + ni*32*64

    i32x8 fa0[4], fb0[2], fa1[4], fb1[2];

    // Prologue: stage tiles 0,1,2; sync tiles 0,1; prefetch f0 -> (fa0,fb0).
    STAGE_A(0, 0); STAGE_A(0, 1); STAGE_B(0, 0); STAGE_B(0, 1);
    STAGE_A(1, 0); STAGE_A(1, 1); STAGE_B(1, 0); STAGE_B(1, 1);
    STAGE_A(2, 0); STAGE_A(2, 1); STAGE_B(2, 0); STAGE_B(2, 1);
    asm volatile("s_waitcnt vmcnt(4)" ::: "memory");   // tiles 0,1 landed
    __builtin_amdgcn_s_barrier();
    __builtin_amdgcn_sched_barrier(0);
    {
        const char* A0 = As[0]; const char* B0 = Bs[0];
#pragma unroll
        for (int mi = 0; mi < 4; ++mi) fa0[mi] = rd32(A0 + aRow + mi * 2048, o0);
#pragma unroll
        for (int ni = 0; ni < 2; ++ni) fb0[ni] = rd32(B0 + bRow + ni * 2048, o0);
    }

#define MFMA8(CA, CB)                                                       \
    __builtin_amdgcn_s_setprio(1);                                          \
    acc[0][0] = __builtin_amdgcn_mfma_scale_f32_32x32x64_f8f6f4(            \
        CA[0], CB[0], acc[0][0], 0, 0, 0, 127, 0, 127);                     \
    acc[0][1] = __builtin_amdgcn_mfma_scale_f32_32x32x64_f8f6f4(            \
        CA[0], CB[1], acc[0][1], 0, 0, 0, 127, 0, 127);                     \
    acc[1][0] = __builtin_amdgcn_mfma_scale_f32_32x32x64_f8f6f4(            \
        CA[1], CB[0], acc[1][0], 0, 0, 0, 127, 0, 127);                     \
    acc[1][1] = __builtin_amdgcn_mfma_scale_f32_32x32x64_f8f6f4(            \
        CA[1], CB[1], acc[1][1], 0, 0, 0, 127, 0, 127);                     \
    acc[2][0] = __builtin_amdgcn_mfma_scale_f32_32x32x64_f8f6f4(            \
        CA[2], CB[0], acc[2][0], 0, 0, 0, 127, 0, 127);                     \
    acc[2][1] = __builtin_amdgcn_mfma_scale_f32_32x32x64_f8f6f4(            \
        CA[2], CB[1], acc[2][1], 0, 0, 0, 127, 0, 127);                     \
    acc[3][0] = __builtin_amdgcn_mfma_scale_f32_32x32x64_f8f6f4(            \
        CA[3], CB[0], acc[3][0], 0, 0, 0, 127, 0, 127);                     \
    acc[3][1] = __builtin_amdgcn_mfma_scale_f32_32x32x64_f8f6f4(            \
        CA[3], CB[1], acc[3][1], 0, 0, 0, 127, 0, 127);                     \
    __builtin_amdgcn_s_setprio(0);

// LLVM SchedGroupMask: MFMA=0x8, VMEM=0x10, DS_READ=0x100 (m137).
#define SGB(mask, n) __builtin_amdgcn_sched_group_barrier(mask, n, 0)

#define BODY(KT, CA, CB, NA, NB)                                            \
  {                                                                         \
    if ((KT) + 3 <= 15) {                                                   \
        STAGE_A((KT) + 3, 0); STAGE_A((KT) + 3, 1);                         \
        STAGE_B((KT) + 3, 0); STAGE_B((KT) + 3, 1);                         \
    }                                                                       \
    if ((KT) < 15) {                                                        \
        const char* An = As[((KT) + 1) & 3];                                \
        const char* Bn = Bs[((KT) + 1) & 3];                                \
        NA[0] = rd32(An + aRow, o0);                                        \
        NA[1] = rd32(An + aRow + 2048, o0);                                 \
        NA[2] = rd32(An + aRow + 4096, o0);                                 \
        NA[3] = rd32(An + aRow + 6144, o0);                                 \
        NB[0] = rd32(Bn + bRow, o0);                                        \
        NB[1] = rd32(Bn + bRow + 2048, o0);                                 \
    }                                                                       \
    MFMA8(CA, CB)                                                           \
    /* pin emission: 4 stages up front, then {6 ds_read, 2 mfma} x4 */      \
    if ((KT) + 3 <= 15) { SGB(0x10, 4); }                                   \
    if ((KT) < 15) {                                                        \
        SGB(0x100, 6); SGB(0x8, 2);                                         \
        SGB(0x100, 6); SGB(0x8, 2);                                         \
        SGB(0x100, 6); SGB(0x8, 2);                                         \
        SGB(0x100, 6); SGB(0x8, 2);                                         \
    } else {                                                                \
        SGB(0x8, 8);                                                        \
    }                                                                       \
    if ((KT) < 15) {                                                        \
        if ((KT) <= 12) { asm volatile("s_waitcnt vmcnt(4)" ::: "memory"); }\
        else            { asm volatile("s_waitcnt vmcnt(0)" ::: "memory"); }\
        __builtin_amdgcn_s_barrier();                                       \
        __builtin_amdgcn_sched_barrier(0);                                  \
    }                                                                       \
  }

    for (int kt2 = 0; kt2 < 8; ++kt2) {
        BODY(kt2 * 2,     fa0, fb0, fa1, fb1);
        BODY(kt2 * 2 + 1, fa1, fb1, fa0, fb0);
    }
#undef STAGE_A
#undef STAGE_B
#undef MFMA8
#undef BODY
#undef SGB

    // Fused reduction per 64x64 (b,t) cell (r10-verified layout).
    // C/D: col = lane&31, row = (reg&3) + 8*(reg>>2) + 4*(lane>>5).
#pragma unroll
    for (int h = 0; h < 2; ++h) {
        float cm[2];
#pragma unroll
        for (int ni = 0; ni < 2; ++ni) {
            float m = acc[h * 2][ni][0];
#pragma unroll
            for (int dm = 0; dm < 2; ++dm)
#pragma unroll
                for (int r = 0; r < 16; ++r)
                    m = fmaxf(m, acc[h * 2 + dm][ni][r]);
            m = fmaxf(m, __shfl_xor(m, 32));   // other 16 rows of the 32-row tile
            cm[ni] = m;                        // col max, replicated over lane>>5
        }
        float s = cm[0] + cm[1];
        s += __shfl_xor(s, 1);
        s += __shfl_xor(s, 2);
        s += __shfl_xor(s, 4);
        s += __shfl_xor(s, 8);
        s += __shfl_xor(s, 16);
        if (lane == 0) {
            int b = tm * 4 + wr * 2 + h;
            int t = tn * 4 + wc;
            aggr[b * 128 + t] = s;
        }
    }
}

// ---------------------------------------------------------------------------
// Parallel loss: stage 1 = one block per x (128 threads over y), stage 2 = sum.
__global__ void loss_stage1(const float* __restrict__ aggr, float* __restrict__ red)
{
    const int x = blockIdx.x;
    const int y = threadIdx.x;
    const float diag = aggr[x * 129];
    float ms = 0.f, mi = 0.f;
    if (y != x) {
        ms = fmaxf(0.2f + aggr[x * 128 + y] - diag, 0.f);
        mi = fmaxf(0.2f + aggr[y * 128 + x] - diag, 0.f);
    }
#pragma unroll
    for (int o = 32; o; o >>= 1) {
        ms = fmaxf(ms, __shfl_xor(ms, o));
        mi = fmaxf(mi, __shfl_xor(mi, o));
    }
    __shared__ float sm[2], si[2];
    if ((y & 63) == 0) { sm[y >> 6] = ms; si[y >> 6] = mi; }
    __syncthreads();
    if (y == 0) red[x] = fmaxf(sm[0], sm[1]) + fmaxf(si[0], si[1]);
}

__global__ void loss_stage2(const float* __restrict__ red, float* __restrict__ out)
{
    float v = red[threadIdx.x];
#pragma unroll
    for (int o = 32; o; o >>= 1) v += __shfl_xor(v, o);
    __shared__ float s[2];
    if ((threadIdx.x & 63) == 0) s[threadIdx.x >> 6] = v;
    __syncthreads();
    if (threadIdx.x == 0) *out = s[0] + s[1];
}

// ---------------------------------------------------------------------------
extern "C" void kernel_launch(void* const* d_in, const int* in_sizes, int n_in,
                              void* d_out, int out_size, void* d_ws, size_t ws_size,
                              hipStream_t stream)
{
    const float* im_set = (const float*)d_in[0];
    const float* s_seq  = (const float*)d_in[1];
    const int*   im_len = (const int*)d_in[2];
    const int*   s_len  = (const int*)d_in[3];
    float* out = (float*)d_out;

    unsigned char* Abf = (unsigned char*)d_ws;                          // 8 MiB
    unsigned char* Bbf = (unsigned char*)d_ws + (8u << 20);             // 8 MiB
    float*         agg = (float*)((char*)d_ws + (16u << 20));           // 64 KiB
    float*         red = (float*)((char*)d_ws + (16u << 20) + 65536);   // 512 B

    conv_kernel<<<16384, 256, 0, stream>>>(im_set, im_len, s_seq, s_len, Abf, Bbf);

    gemm_aggr_kernel<<<dim3(32, 32), 512, 0, stream>>>(Abf, Bbf, agg);

    loss_stage1<<<128, 128, 0, stream>>>(agg, red);
    loss_stage2<<<1, 128, 0, stream>>>(red, out);
}

// Round 17
// 65.322 us; speedup vs baseline: 1.2364x; 1.2364x over previous
//
#include <hip/hip_runtime.h>

typedef __attribute__((ext_vector_type(4))) int   i32x4;
typedef __attribute__((ext_vector_type(8))) int   i32x8;
typedef __attribute__((ext_vector_type(16))) float f32x16;

// ---------------------------------------------------------------------------
// f32 -> fp4 e2m1 (nearest), values {0,.5,1,1.5,2,3,4,6} with sign.
__device__ __forceinline__ unsigned enc4(float v) {
    unsigned s = (__float_as_uint(v) >> 31) << 3;
    float a = fabsf(v);
    unsigned c = a < 0.25f ? 0u : a < 0.75f ? 1u : a < 1.25f ? 2u : a < 1.75f ? 3u
               : a < 2.5f  ? 4u : a < 3.5f  ? 5u : a < 5.0f  ? 6u : 7u;
    return s | c;
}

// Fused slice + convert(f32 -> packed fp4 e2m1) + mask-zero for BOTH inputs.
// Output: row-major [8192 rows][512 B] (1024 k-elems x 0.5 B, elem k at
// nibble k&7 of dword k>>3 -- dense little-endian).
// Each thread: 8 consecutive elems -> 1 dword. 256 thr = 2 rows/block.
__global__ void conv_kernel(const float* __restrict__ im, const int* __restrict__ iml,
                            const float* __restrict__ ss, const int* __restrict__ sl,
                            unsigned* __restrict__ Ad, unsigned* __restrict__ Bd)
{
    int bid = blockIdx.x;
    const float* src; const int* len; unsigned* dst; int rawL, adj;
    if (bid < 4096) { src = im; len = iml; dst = Ad; rawL = 65; adj = -1; }
    else { bid -= 4096; src = ss; len = sl; dst = Bd; rawL = 67; adj = -3; }
    int t = threadIdx.x;
    int m = bid * 2 + (t >> 7);        // output row 0..8191
    int c = (t & 127) * 8;             // elem offset within row
    int b = m >> 6;
    int i = m & 63;
    int lim = len[b] + adj;
    float4 v0 = make_float4(0.f, 0.f, 0.f, 0.f), v1 = v0;
    if (i < lim) {
        const float* p = src + ((size_t)(b * rawL + 1 + i) << 10) + c;
        v0 = *(const float4*)p;
        v1 = *(const float4*)(p + 4);
    }
    unsigned w = enc4(v0.x) | (enc4(v0.y) << 4) | (enc4(v0.z) << 8)  | (enc4(v0.w) << 12)
               | (enc4(v1.x) << 16) | (enc4(v1.y) << 20) | (enc4(v1.z) << 24) | (enc4(v1.w) << 28);
    dst[m * 128 + (t & 127)] = w;
}

// ---------------------------------------------------------------------------
__device__ __forceinline__ void gload_lds16(const void* g, void* l) {
    __builtin_amdgcn_global_load_lds((const __attribute__((address_space(1))) void*)g,
                                     (__attribute__((address_space(3))) void*)l,
                                     16, 0, 0);
}

__device__ __forceinline__ i32x8 dup4(i32x4 a) {
    return __builtin_shufflevector(a, a, 0, 1, 2, 3, 0, 1, 2, 3);
}

// 256x256 tile, BK=64 (fp4: 32B rows), 8 waves (2M x 4N), per-wave 128x64.
// Ring-4 LDS (64 KiB) + register-double-buffered fragments (r13-verified
// schedule). fp4 halves both pipes vs fp8: A-frag = ONE b128/lane, 6 b128
// prefetch reads + 2 staging gloads per body (whole 8KB operand tile = one
// 512x16B gload). 32B rows -> linear LDS is <=2-way banked (free) -> no
// swizzle. Ledger: stage(kt+3); gates vmcnt(2) kt<=12, vmcnt(0) kt=13,14.
// MFMA: mfma_scale_f32_32x32x64_f8f6f4, cbsz=blgp=4 (fp4), scale=1 (E8M0
// 127); v8i32 operands built by dup4 (high half ignored for fp4).
// C/D (r10-verified): col=lane&31, row=(reg&3)+8*(reg>>2)+4*(lane>>5).
__global__ void __launch_bounds__(512) gemm_aggr_kernel(const unsigned char* __restrict__ A,
                                                        const unsigned char* __restrict__ B,
                                                        float* __restrict__ aggr)
{
    __shared__ __align__(16) char As[4][8192];   // 256 rows x 32 B per slot
    __shared__ __align__(16) char Bs[4][8192];

    const int tid  = threadIdx.x;
    const int lane = tid & 63;
    const int wid  = tid >> 6;        // 0..7
    const int wr   = wid >> 2;        // 0..1 : 128-row half of BM=256
    const int wc   = wid & 3;         // 0..3 : 64-col quarter of BN=256
    const int tm   = blockIdx.y;      // 0..31
    const int tn   = blockIdx.x;      // 0..31

    const int r31 = lane & 31;
    const int g2  = lane >> 5;        // 0..1

    // Staging: whole 8KB operand tile in one gload (512 thr x 16 B).
    // Thread t: LDS off t*16 -> row t>>1, k-half t&1. Global row stride 512B.
    const unsigned char* gA_t = A + ((size_t)(tm * 256 + (tid >> 1)) << 9) + (tid & 1) * 16;
    const unsigned char* gB_t = B + ((size_t)(tn * 256 + (tid >> 1)) << 9) + (tid & 1) * 16;

#define STAGE_A(kt) gload_lds16(gA_t + (kt) * 32, As[(kt) & 3] + tid * 16)
#define STAGE_B(kt) gload_lds16(gB_t + (kt) * 32, Bs[(kt) & 3] + tid * 16)

    f32x16 acc[4][2];   // [32-row block mi][32-col block ni]
#pragma unroll
    for (int mi = 0; mi < 4; ++mi)
#pragma unroll
        for (int ni = 0; ni < 2; ++ni)
#pragma unroll
            for (int r = 0; r < 16; ++r)
                acc[mi][ni][r] = 0.f;

    // Fragment byte offsets within a slot: row*32 + g2*16.
    const int aOff = (wr * 128 + r31) * 32 + g2 * 16;   // + mi*1024
    const int bOff = (wc * 64 + r31) * 32 + g2 * 16;    // + ni*1024

    i32x4 fa0[4], fb0[2], fa1[4], fb1[2];

    // Prologue: stage tiles 0,1,2; wait tiles 0,1; prefetch tile 0 fragments.
    STAGE_A(0); STAGE_B(0);
    STAGE_A(1); STAGE_B(1);
    STAGE_A(2); STAGE_B(2);
    asm volatile("s_waitcnt vmcnt(2)" ::: "memory");   // tiles 0,1 landed
    __builtin_amdgcn_s_barrier();
    __builtin_amdgcn_sched_barrier(0);
    {
        const char* A0 = As[0]; const char* B0 = Bs[0];
#pragma unroll
        for (int mi = 0; mi < 4; ++mi) fa0[mi] = *(const i32x4*)(A0 + aOff + mi * 1024);
#pragma unroll
        for (int ni = 0; ni < 2; ++ni) fb0[ni] = *(const i32x4*)(B0 + bOff + ni * 1024);
    }

#define MFMA8(CA, CB)                                                       \
    __builtin_amdgcn_s_setprio(1);                                          \
    acc[0][0] = __builtin_amdgcn_mfma_scale_f32_32x32x64_f8f6f4(            \
        dup4(CA[0]), dup4(CB[0]), acc[0][0], 4, 4, 0, 127, 0, 127);         \
    acc[0][1] = __builtin_amdgcn_mfma_scale_f32_32x32x64_f8f6f4(            \
        dup4(CA[0]), dup4(CB[1]), acc[0][1], 4, 4, 0, 127, 0, 127);         \
    acc[1][0] = __builtin_amdgcn_mfma_scale_f32_32x32x64_f8f6f4(            \
        dup4(CA[1]), dup4(CB[0]), acc[1][0], 4, 4, 0, 127, 0, 127);         \
    acc[1][1] = __builtin_amdgcn_mfma_scale_f32_32x32x64_f8f6f4(            \
        dup4(CA[1]), dup4(CB[1]), acc[1][1], 4, 4, 0, 127, 0, 127);         \
    acc[2][0] = __builtin_amdgcn_mfma_scale_f32_32x32x64_f8f6f4(            \
        dup4(CA[2]), dup4(CB[0]), acc[2][0], 4, 4, 0, 127, 0, 127);         \
    acc[2][1] = __builtin_amdgcn_mfma_scale_f32_32x32x64_f8f6f4(            \
        dup4(CA[2]), dup4(CB[1]), acc[2][1], 4, 4, 0, 127, 0, 127);         \
    acc[3][0] = __builtin_amdgcn_mfma_scale_f32_32x32x64_f8f6f4(            \
        dup4(CA[3]), dup4(CB[0]), acc[3][0], 4, 4, 0, 127, 0, 127);         \
    acc[3][1] = __builtin_amdgcn_mfma_scale_f32_32x32x64_f8f6f4(            \
        dup4(CA[3]), dup4(CB[1]), acc[3][1], 4, 4, 0, 127, 0, 127);         \
    __builtin_amdgcn_s_setprio(0);

#define BODY(KT, CA, CB, NA, NB)                                            \
  {                                                                         \
    if ((KT) + 3 <= 15) { STAGE_A((KT) + 3); STAGE_B((KT) + 3); }           \
    if ((KT) < 15) {                                                        \
        const char* An = As[((KT) + 1) & 3];                                \
        const char* Bn = Bs[((KT) + 1) & 3];                                \
        NA[0] = *(const i32x4*)(An + aOff);                                 \
        NA[1] = *(const i32x4*)(An + aOff + 1024);                          \
        NA[2] = *(const i32x4*)(An + aOff + 2048);                          \
        NA[3] = *(const i32x4*)(An + aOff + 3072);                          \
        NB[0] = *(const i32x4*)(Bn + bOff);                                 \
        NB[1] = *(const i32x4*)(Bn + bOff + 1024);                          \
    }                                                                       \
    MFMA8(CA, CB)                                                           \
    if ((KT) < 15) {                                                        \
        if ((KT) <= 12) { asm volatile("s_waitcnt vmcnt(2)" ::: "memory"); }\
        else            { asm volatile("s_waitcnt vmcnt(0)" ::: "memory"); }\
        __builtin_amdgcn_s_barrier();                                       \
        __builtin_amdgcn_sched_barrier(0);                                  \
    }                                                                       \
  }

    for (int kt2 = 0; kt2 < 8; ++kt2) {
        BODY(kt2 * 2,     fa0, fb0, fa1, fb1);
        BODY(kt2 * 2 + 1, fa1, fb1, fa0, fb0);
    }
#undef STAGE_A
#undef STAGE_B
#undef MFMA8
#undef BODY

    // Fused reduction per 64x64 (b,t) cell (r10-verified layout).
    // C/D: col = lane&31, row = (reg&3) + 8*(reg>>2) + 4*(lane>>5).
#pragma unroll
    for (int h = 0; h < 2; ++h) {
        float cm[2];
#pragma unroll
        for (int ni = 0; ni < 2; ++ni) {
            float m = acc[h * 2][ni][0];
#pragma unroll
            for (int dm = 0; dm < 2; ++dm)
#pragma unroll
                for (int r = 0; r < 16; ++r)
                    m = fmaxf(m, acc[h * 2 + dm][ni][r]);
            m = fmaxf(m, __shfl_xor(m, 32));   // other 16 rows of the 32-row tile
            cm[ni] = m;                        // col max, replicated over lane>>5
        }
        float s = cm[0] + cm[1];
        s += __shfl_xor(s, 1);
        s += __shfl_xor(s, 2);
        s += __shfl_xor(s, 4);
        s += __shfl_xor(s, 8);
        s += __shfl_xor(s, 16);
        if (lane == 0) {
            int b = tm * 4 + wr * 2 + h;
            int t = tn * 4 + wc;
            aggr[b * 128 + t] = s;
        }
    }
}

// ---------------------------------------------------------------------------
// Parallel loss: stage 1 = one block per x (128 threads over y), stage 2 = sum.
__global__ void loss_stage1(const float* __restrict__ aggr, float* __restrict__ red)
{
    const int x = blockIdx.x;
    const int y = threadIdx.x;
    const float diag = aggr[x * 129];
    float ms = 0.f, mi = 0.f;
    if (y != x) {
        ms = fmaxf(0.2f + aggr[x * 128 + y] - diag, 0.f);
        mi = fmaxf(0.2f + aggr[y * 128 + x] - diag, 0.f);
    }
#pragma unroll
    for (int o = 32; o; o >>= 1) {
        ms = fmaxf(ms, __shfl_xor(ms, o));
        mi = fmaxf(mi, __shfl_xor(mi, o));
    }
    __shared__ float sm[2], si[2];
    if ((y & 63) == 0) { sm[y >> 6] = ms; si[y >> 6] = mi; }
    __syncthreads();
    if (y == 0) red[x] = fmaxf(sm[0], sm[1]) + fmaxf(si[0], si[1]);
}

__global__ void loss_stage2(const float* __restrict__ red, float* __restrict__ out)
{
    float v = red[threadIdx.x];
#pragma unroll
    for (int o = 32; o; o >>= 1) v += __shfl_xor(v, o);
    __shared__ float s[2];
    if ((threadIdx.x & 63) == 0) s[threadIdx.x >> 6] = v;
    __syncthreads();
    if (threadIdx.x == 0) *out = s[0] + s[1];
}

// ---------------------------------------------------------------------------
extern "C" void kernel_launch(void* const* d_in, const int* in_sizes, int n_in,
                              void* d_out, int out_size, void* d_ws, size_t ws_size,
                              hipStream_t stream)
{
    const float* im_set = (const float*)d_in[0];
    const float* s_seq  = (const float*)d_in[1];
    const int*   im_len = (const int*)d_in[2];
    const int*   s_len  = (const int*)d_in[3];
    float* out = (float*)d_out;

    unsigned char* Abf = (unsigned char*)d_ws;                          // 4 MiB
    unsigned char* Bbf = (unsigned char*)d_ws + (4u << 20);             // 4 MiB
    float*         agg = (float*)((char*)d_ws + (8u << 20));            // 64 KiB
    float*         red = (float*)((char*)d_ws + (8u << 20) + 65536);    // 512 B

    conv_kernel<<<8192, 256, 0, stream>>>(im_set, im_len, s_seq, s_len,
                                          (unsigned*)Abf, (unsigned*)Bbf);

    gemm_aggr_kernel<<<dim3(32, 32), 512, 0, stream>>>(Abf, Bbf, agg);

    loss_stage1<<<128, 128, 0, stream>>>(agg, red);
    loss_stage2<<<1, 128, 0, stream>>>(red, out);
}

// Round 18
// 56.036 us; speedup vs baseline: 1.4413x; 1.1657x over previous
//
#include <hip/hip_runtime.h>

typedef __attribute__((ext_vector_type(4))) int   i32x4;
typedef __attribute__((ext_vector_type(8))) int   i32x8;
typedef __attribute__((ext_vector_type(16))) float f32x16;

// ---------------------------------------------------------------------------
// f32 -> fp4 e2m1 (nearest), values {0,.5,1,1.5,2,3,4,6} with sign.
__device__ __forceinline__ unsigned enc4(float v) {
    unsigned s = (__float_as_uint(v) >> 31) << 3;
    float a = fabsf(v);
    unsigned c = a < 0.25f ? 0u : a < 0.75f ? 1u : a < 1.25f ? 2u : a < 1.75f ? 3u
               : a < 2.5f  ? 4u : a < 3.5f  ? 5u : a < 5.0f  ? 6u : 7u;
    return s | c;
}

// Fused slice + convert(f32 -> packed fp4 e2m1) + mask-zero, writing the
// operands PRE-TILED in GEMM LDS-slot order:
//   dword addr = panel(m>>8)*32768 + kt(c>>6)*2048 + h((c>>5)&1)*1024
//              + row(m&255)*4 + q((c>>3)&3)
// so each GEMM staging op is ONE contiguous 8KB gload_lds, and fragment
// reads (g2*4096 + row*16) are canonical conflict-free b128.
__global__ void conv_kernel(const float* __restrict__ im, const int* __restrict__ iml,
                            const float* __restrict__ ss, const int* __restrict__ sl,
                            unsigned* __restrict__ Ad, unsigned* __restrict__ Bd)
{
    int bid = blockIdx.x;
    const float* src; const int* len; unsigned* dst; int rawL, adj;
    if (bid < 4096) { src = im; len = iml; dst = Ad; rawL = 65; adj = -1; }
    else { bid -= 4096; src = ss; len = sl; dst = Bd; rawL = 67; adj = -3; }
    int t = threadIdx.x;
    int m = bid * 2 + (t >> 7);        // output row 0..8191
    int c = (t & 127) * 8;             // elem offset within row
    int b = m >> 6;
    int i = m & 63;
    int lim = len[b] + adj;
    float4 v0 = make_float4(0.f, 0.f, 0.f, 0.f), v1 = v0;
    if (i < lim) {
        const float* p = src + ((size_t)(b * rawL + 1 + i) << 10) + c;
        v0 = *(const float4*)p;
        v1 = *(const float4*)(p + 4);
    }
    unsigned w = enc4(v0.x) | (enc4(v0.y) << 4) | (enc4(v0.z) << 8)  | (enc4(v0.w) << 12)
               | (enc4(v1.x) << 16) | (enc4(v1.y) << 20) | (enc4(v1.z) << 24) | (enc4(v1.w) << 28);
    dst[(m >> 8) * 32768 + (c >> 6) * 2048 + ((c >> 5) & 1) * 1024
        + (m & 255) * 4 + ((c >> 3) & 3)] = w;
}

// ---------------------------------------------------------------------------
__device__ __forceinline__ void gload_lds16(const void* g, void* l) {
    __builtin_amdgcn_global_load_lds((const __attribute__((address_space(1))) void*)g,
                                     (__attribute__((address_space(3))) void*)l,
                                     16, 0, 0);
}

__device__ __forceinline__ i32x8 dup4(i32x4 a) {
    return __builtin_shufflevector(a, a, 0, 1, 2, 3, 0, 1, 2, 3);
}

// 256x256 tile, BK=64 (fp4), 8 waves (2M x 4N), per-wave 128x64.
// Ring-4 LDS (64 KiB) + register-double-buffered fragments (r13 schedule).
// Operands stored pre-tiled [panel][kt][h=k-half][row][16B] (see conv):
//  - staging = 1 contiguous 8KB gload_lds per operand per body;
//  - fragment read addr = g2*4096 + row*16 -> 8-lane groups hit banks 0..31
//    exactly once = ZERO-conflict b128 (r17's row-major 32B rows were 2-way).
// Lane register content identical to r17 (row, k-half unchanged).
// Ledger: stage(kt+3); gates vmcnt(2) kt<=12, vmcnt(0) kt=13,14.
// MFMA: mfma_scale_f32_32x32x64_f8f6f4, cbsz=blgp=4 (fp4), scale=1 (E8M0 127).
// C/D (r10-verified): col=lane&31, row=(reg&3)+8*(reg>>2)+4*(lane>>5).
__global__ void __launch_bounds__(512) gemm_aggr_kernel(const unsigned char* __restrict__ A,
                                                        const unsigned char* __restrict__ B,
                                                        float* __restrict__ aggr)
{
    __shared__ __align__(16) char As[4][8192];   // [h:2][row:256][16B] per slot
    __shared__ __align__(16) char Bs[4][8192];

    const int tid  = threadIdx.x;
    const int lane = tid & 63;
    const int wid  = tid >> 6;        // 0..7
    const int wr   = wid >> 2;        // 0..1 : 128-row half of BM=256
    const int wc   = wid & 3;         // 0..3 : 64-col quarter of BN=256
    const int tm   = blockIdx.y;      // 0..31
    const int tn   = blockIdx.x;      // 0..31

    const int r31 = lane & 31;
    const int g2  = lane >> 5;        // 0..1

    // Staging: panel base + kt*8192 + tid*16 -- fully contiguous 8KB.
    const unsigned char* gA_t = A + (size_t)tm * 131072 + tid * 16;
    const unsigned char* gB_t = B + (size_t)tn * 131072 + tid * 16;

#define STAGE_A(kt) gload_lds16(gA_t + (kt) * 8192, As[(kt) & 3] + tid * 16)
#define STAGE_B(kt) gload_lds16(gB_t + (kt) * 8192, Bs[(kt) & 3] + tid * 16)

    f32x16 acc[4][2];   // [32-row block mi][32-col block ni]
#pragma unroll
    for (int mi = 0; mi < 4; ++mi)
#pragma unroll
        for (int ni = 0; ni < 2; ++ni)
#pragma unroll
            for (int r = 0; r < 16; ++r)
                acc[mi][ni][r] = 0.f;

    // Fragment byte offsets within a slot: g2*4096 + row*16.
    const int aOff = g2 * 4096 + (wr * 128 + r31) * 16;   // + mi*512
    const int bOff = g2 * 4096 + (wc * 64 + r31) * 16;    // + ni*512

    i32x4 fa0[4], fb0[2], fa1[4], fb1[2];

    // Prologue: stage tiles 0,1,2; wait tiles 0,1; prefetch tile 0 fragments.
    STAGE_A(0); STAGE_B(0);
    STAGE_A(1); STAGE_B(1);
    STAGE_A(2); STAGE_B(2);
    asm volatile("s_waitcnt vmcnt(2)" ::: "memory");   // tiles 0,1 landed
    __builtin_amdgcn_s_barrier();
    __builtin_amdgcn_sched_barrier(0);
    {
        const char* A0 = As[0]; const char* B0 = Bs[0];
#pragma unroll
        for (int mi = 0; mi < 4; ++mi) fa0[mi] = *(const i32x4*)(A0 + aOff + mi * 512);
#pragma unroll
        for (int ni = 0; ni < 2; ++ni) fb0[ni] = *(const i32x4*)(B0 + bOff + ni * 512);
    }

#define MFMA8(CA, CB)                                                       \
    __builtin_amdgcn_s_setprio(1);                                          \
    acc[0][0] = __builtin_amdgcn_mfma_scale_f32_32x32x64_f8f6f4(            \
        dup4(CA[0]), dup4(CB[0]), acc[0][0], 4, 4, 0, 127, 0, 127);         \
    acc[0][1] = __builtin_amdgcn_mfma_scale_f32_32x32x64_f8f6f4(            \
        dup4(CA[0]), dup4(CB[1]), acc[0][1], 4, 4, 0, 127, 0, 127);         \
    acc[1][0] = __builtin_amdgcn_mfma_scale_f32_32x32x64_f8f6f4(            \
        dup4(CA[1]), dup4(CB[0]), acc[1][0], 4, 4, 0, 127, 0, 127);         \
    acc[1][1] = __builtin_amdgcn_mfma_scale_f32_32x32x64_f8f6f4(            \
        dup4(CA[1]), dup4(CB[1]), acc[1][1], 4, 4, 0, 127, 0, 127);         \
    acc[2][0] = __builtin_amdgcn_mfma_scale_f32_32x32x64_f8f6f4(            \
        dup4(CA[2]), dup4(CB[0]), acc[2][0], 4, 4, 0, 127, 0, 127);         \
    acc[2][1] = __builtin_amdgcn_mfma_scale_f32_32x32x64_f8f6f4(            \
        dup4(CA[2]), dup4(CB[1]), acc[2][1], 4, 4, 0, 127, 0, 127);         \
    acc[3][0] = __builtin_amdgcn_mfma_scale_f32_32x32x64_f8f6f4(            \
        dup4(CA[3]), dup4(CB[0]), acc[3][0], 4, 4, 0, 127, 0, 127);         \
    acc[3][1] = __builtin_amdgcn_mfma_scale_f32_32x32x64_f8f6f4(            \
        dup4(CA[3]), dup4(CB[1]), acc[3][1], 4, 4, 0, 127, 0, 127);         \
    __builtin_amdgcn_s_setprio(0);

#define BODY(KT, CA, CB, NA, NB)                                            \
  {                                                                         \
    if ((KT) + 3 <= 15) { STAGE_A((KT) + 3); STAGE_B((KT) + 3); }           \
    if ((KT) < 15) {                                                        \
        const char* An = As[((KT) + 1) & 3];                                \
        const char* Bn = Bs[((KT) + 1) & 3];                                \
        NA[0] = *(const i32x4*)(An + aOff);                                 \
        NA[1] = *(const i32x4*)(An + aOff + 512);                           \
        NA[2] = *(const i32x4*)(An + aOff + 1024);                          \
        NA[3] = *(const i32x4*)(An + aOff + 1536);                          \
        NB[0] = *(const i32x4*)(Bn + bOff);                                 \
        NB[1] = *(const i32x4*)(Bn + bOff + 512);                           \
    }                                                                       \
    MFMA8(CA, CB)                                                           \
    if ((KT) < 15) {                                                        \
        if ((KT) <= 12) { asm volatile("s_waitcnt vmcnt(2)" ::: "memory"); }\
        else            { asm volatile("s_waitcnt vmcnt(0)" ::: "memory"); }\
        __builtin_amdgcn_s_barrier();                                       \
        __builtin_amdgcn_sched_barrier(0);                                  \
    }                                                                       \
  }

    for (int kt2 = 0; kt2 < 8; ++kt2) {
        BODY(kt2 * 2,     fa0, fb0, fa1, fb1);
        BODY(kt2 * 2 + 1, fa1, fb1, fa0, fb0);
    }
#undef STAGE_A
#undef STAGE_B
#undef MFMA8
#undef BODY

    // Fused reduction per 64x64 (b,t) cell (r10-verified layout).
    // C/D: col = lane&31, row = (reg&3) + 8*(reg>>2) + 4*(lane>>5).
#pragma unroll
    for (int h = 0; h < 2; ++h) {
        float cm[2];
#pragma unroll
        for (int ni = 0; ni < 2; ++ni) {
            float m = acc[h * 2][ni][0];
#pragma unroll
            for (int dm = 0; dm < 2; ++dm)
#pragma unroll
                for (int r = 0; r < 16; ++r)
                    m = fmaxf(m, acc[h * 2 + dm][ni][r]);
            m = fmaxf(m, __shfl_xor(m, 32));   // other 16 rows of the 32-row tile
            cm[ni] = m;                        // col max, replicated over lane>>5
        }
        float s = cm[0] + cm[1];
        s += __shfl_xor(s, 1);
        s += __shfl_xor(s, 2);
        s += __shfl_xor(s, 4);
        s += __shfl_xor(s, 8);
        s += __shfl_xor(s, 16);
        if (lane == 0) {
            int b = tm * 4 + wr * 2 + h;
            int t = tn * 4 + wc;
            aggr[b * 128 + t] = s;
        }
    }
}

// ---------------------------------------------------------------------------
// Parallel loss: stage 1 = one block per x (128 threads over y), stage 2 = sum.
__global__ void loss_stage1(const float* __restrict__ aggr, float* __restrict__ red)
{
    const int x = blockIdx.x;
    const int y = threadIdx.x;
    const float diag = aggr[x * 129];
    float ms = 0.f, mi = 0.f;
    if (y != x) {
        ms = fmaxf(0.2f + aggr[x * 128 + y] - diag, 0.f);
        mi = fmaxf(0.2f + aggr[y * 128 + x] - diag, 0.f);
    }
#pragma unroll
    for (int o = 32; o; o >>= 1) {
        ms = fmaxf(ms, __shfl_xor(ms, o));
        mi = fmaxf(mi, __shfl_xor(mi, o));
    }
    __shared__ float sm[2], si[2];
    if ((y & 63) == 0) { sm[y >> 6] = ms; si[y >> 6] = mi; }
    __syncthreads();
    if (y == 0) red[x] = fmaxf(sm[0], sm[1]) + fmaxf(si[0], si[1]);
}

__global__ void loss_stage2(const float* __restrict__ red, float* __restrict__ out)
{
    float v = red[threadIdx.x];
#pragma unroll
    for (int o = 32; o; o >>= 1) v += __shfl_xor(v, o);
    __shared__ float s[2];
    if ((threadIdx.x & 63) == 0) s[threadIdx.x >> 6] = v;
    __syncthreads();
    if (threadIdx.x == 0) *out = s[0] + s[1];
}

// ---------------------------------------------------------------------------
extern "C" void kernel_launch(void* const* d_in, const int* in_sizes, int n_in,
                              void* d_out, int out_size, void* d_ws, size_t ws_size,
                              hipStream_t stream)
{
    const float* im_set = (const float*)d_in[0];
    const float* s_seq  = (const float*)d_in[1];
    const int*   im_len = (const int*)d_in[2];
    const int*   s_len  = (const int*)d_in[3];
    float* out = (float*)d_out;

    unsigned char* Abf = (unsigned char*)d_ws;                          // 4 MiB
    unsigned char* Bbf = (unsigned char*)d_ws + (4u << 20);             // 4 MiB
    float*         agg = (float*)((char*)d_ws + (8u << 20));            // 64 KiB
    float*         red = (float*)((char*)d_ws + (8u << 20) + 65536);    // 512 B

    conv_kernel<<<8192, 256, 0, stream>>>(im_set, im_len, s_seq, s_len,
                                          (unsigned*)Abf, (unsigned*)Bbf);

    gemm_aggr_kernel<<<dim3(32, 32), 512, 0, stream>>>(Abf, Bbf, agg);

    loss_stage1<<<128, 128, 0, stream>>>(agg, red);
    loss_stage2<<<1, 128, 0, stream>>>(red, out);
}

// Round 19
// 55.003 us; speedup vs baseline: 1.4683x; 1.0188x over previous
//
#include <hip/hip_runtime.h>

typedef __attribute__((ext_vector_type(4))) int   i32x4;
typedef __attribute__((ext_vector_type(8))) int   i32x8;
typedef __attribute__((ext_vector_type(16))) float f32x16;

// ---------------------------------------------------------------------------
// f32 -> fp4 e2m1 (nearest), values {0,.5,1,1.5,2,3,4,6} with sign.
__device__ __forceinline__ unsigned enc4(float v) {
    unsigned s = (__float_as_uint(v) >> 31) << 3;
    float a = fabsf(v);
    unsigned c = a < 0.25f ? 0u : a < 0.75f ? 1u : a < 1.25f ? 2u : a < 1.75f ? 3u
               : a < 2.5f  ? 4u : a < 3.5f  ? 5u : a < 5.0f  ? 6u : 7u;
    return s | c;
}

// Fused slice + convert(f32 -> packed fp4 e2m1) + mask-zero, writing the
// operands PRE-TILED in GEMM LDS-slot order (r18-verified):
//   dword addr = panel(m>>8)*32768 + kt(c>>6)*2048 + h((c>>5)&1)*1024
//              + row(m&255)*4 + q((c>>3)&3)
__global__ void conv_kernel(const float* __restrict__ im, const int* __restrict__ iml,
                            const float* __restrict__ ss, const int* __restrict__ sl,
                            unsigned* __restrict__ Ad, unsigned* __restrict__ Bd)
{
    int bid = blockIdx.x;
    const float* src; const int* len; unsigned* dst; int rawL, adj;
    if (bid < 4096) { src = im; len = iml; dst = Ad; rawL = 65; adj = -1; }
    else { bid -= 4096; src = ss; len = sl; dst = Bd; rawL = 67; adj = -3; }
    int t = threadIdx.x;
    int m = bid * 2 + (t >> 7);        // output row 0..8191
    int c = (t & 127) * 8;             // elem offset within row
    int b = m >> 6;
    int i = m & 63;
    int lim = len[b] + adj;
    float4 v0 = make_float4(0.f, 0.f, 0.f, 0.f), v1 = v0;
    if (i < lim) {
        const float* p = src + ((size_t)(b * rawL + 1 + i) << 10) + c;
        v0 = *(const float4*)p;
        v1 = *(const float4*)(p + 4);
    }
    unsigned w = enc4(v0.x) | (enc4(v0.y) << 4) | (enc4(v0.z) << 8)  | (enc4(v0.w) << 12)
               | (enc4(v1.x) << 16) | (enc4(v1.y) << 20) | (enc4(v1.z) << 24) | (enc4(v1.w) << 28);
    dst[(m >> 8) * 32768 + (c >> 6) * 2048 + ((c >> 5) & 1) * 1024
        + (m & 255) * 4 + ((c >> 3) & 3)] = w;
}

// ---------------------------------------------------------------------------
__device__ __forceinline__ void gload_lds16(const void* g, void* l) {
    __builtin_amdgcn_global_load_lds((const __attribute__((address_space(1))) void*)g,
                                     (__attribute__((address_space(3))) void*)l,
                                     16, 0, 0);
}

__device__ __forceinline__ i32x8 dup4(i32x4 a) {
    return __builtin_shufflevector(a, a, 0, 1, 2, 3, 0, 1, 2, 3);
}

// 256x256 tile, BK=64 (fp4), 8 waves (2M x 4N), per-wave 128x64.
// Ring-4 LDS (64 KiB) + register-double-buffered fragments + pre-tiled
// operands (r18-verified: 0 bank conflicts, 1-gload staging per operand).
// NEW (r19): WAVE-ROLE ANTI-PHASE. SIMD = wid%4, so wid<4 / wid>=4 puts one
// wave of each role on every SIMD. Role-A body: prefetch -> MFMA; role-B:
// MFMA -> prefetch. Legal pure reorder (MFMA(kt) uses regs loaded in body
// kt-1; prefetch(kt+1) independent) -> each SIMD has one wave feeding the
// matrix pipe while its partner feeds the LDS pipe (breaks CU-wide
// read-burst/MFMA-burst lockstep that kept both pipes <40% busy).
// Ledger unchanged: stage(kt+3); gates vmcnt(2) kt<=12, vmcnt(0) kt=13,14.
// MFMA: mfma_scale_f32_32x32x64_f8f6f4, cbsz=blgp=4 (fp4), scale=1 (E8M0 127).
// C/D (r10-verified): col=lane&31, row=(reg&3)+8*(reg>>2)+4*(lane>>5).
__global__ void __launch_bounds__(512) gemm_aggr_kernel(const unsigned char* __restrict__ A,
                                                        const unsigned char* __restrict__ B,
                                                        float* __restrict__ aggr)
{
    __shared__ __align__(16) char As[4][8192];   // [h:2][row:256][16B] per slot
    __shared__ __align__(16) char Bs[4][8192];

    const int tid  = threadIdx.x;
    const int lane = tid & 63;
    const int wid  = tid >> 6;        // 0..7
    const int wr   = wid >> 2;        // 0..1 : 128-row half of BM=256
    const int wc   = wid & 3;         // 0..3 : 64-col quarter of BN=256
    const int tm   = blockIdx.y;      // 0..31
    const int tn   = blockIdx.x;      // 0..31

    const int r31 = lane & 31;
    const int g2  = lane >> 5;        // 0..1
    const bool roleA = (wid < 4);     // one role-A + one role-B per SIMD

    // Staging: panel base + kt*8192 + tid*16 -- fully contiguous 8KB.
    const unsigned char* gA_t = A + (size_t)tm * 131072 + tid * 16;
    const unsigned char* gB_t = B + (size_t)tn * 131072 + tid * 16;

#define STAGE_A(kt) gload_lds16(gA_t + (kt) * 8192, As[(kt) & 3] + tid * 16)
#define STAGE_B(kt) gload_lds16(gB_t + (kt) * 8192, Bs[(kt) & 3] + tid * 16)

    f32x16 acc[4][2];   // [32-row block mi][32-col block ni]
#pragma unroll
    for (int mi = 0; mi < 4; ++mi)
#pragma unroll
        for (int ni = 0; ni < 2; ++ni)
#pragma unroll
            for (int r = 0; r < 16; ++r)
                acc[mi][ni][r] = 0.f;

    // Fragment byte offsets within a slot: g2*4096 + row*16.
    const int aOff = g2 * 4096 + (wr * 128 + r31) * 16;   // + mi*512
    const int bOff = g2 * 4096 + (wc * 64 + r31) * 16;    // + ni*512

    i32x4 fa0[4], fb0[2], fa1[4], fb1[2];

    // Prologue: stage tiles 0,1,2; wait tiles 0,1; prefetch tile 0 fragments.
    STAGE_A(0); STAGE_B(0);
    STAGE_A(1); STAGE_B(1);
    STAGE_A(2); STAGE_B(2);
    asm volatile("s_waitcnt vmcnt(2)" ::: "memory");   // tiles 0,1 landed
    __builtin_amdgcn_s_barrier();
    __builtin_amdgcn_sched_barrier(0);
    {
        const char* A0 = As[0]; const char* B0 = Bs[0];
#pragma unroll
        for (int mi = 0; mi < 4; ++mi) fa0[mi] = *(const i32x4*)(A0 + aOff + mi * 512);
#pragma unroll
        for (int ni = 0; ni < 2; ++ni) fb0[ni] = *(const i32x4*)(B0 + bOff + ni * 512);
    }

#define MFMA8(CA, CB)                                                       \
    __builtin_amdgcn_s_setprio(1);                                          \
    acc[0][0] = __builtin_amdgcn_mfma_scale_f32_32x32x64_f8f6f4(            \
        dup4(CA[0]), dup4(CB[0]), acc[0][0], 4, 4, 0, 127, 0, 127);         \
    acc[0][1] = __builtin_amdgcn_mfma_scale_f32_32x32x64_f8f6f4(            \
        dup4(CA[0]), dup4(CB[1]), acc[0][1], 4, 4, 0, 127, 0, 127);         \
    acc[1][0] = __builtin_amdgcn_mfma_scale_f32_32x32x64_f8f6f4(            \
        dup4(CA[1]), dup4(CB[0]), acc[1][0], 4, 4, 0, 127, 0, 127);         \
    acc[1][1] = __builtin_amdgcn_mfma_scale_f32_32x32x64_f8f6f4(            \
        dup4(CA[1]), dup4(CB[1]), acc[1][1], 4, 4, 0, 127, 0, 127);         \
    acc[2][0] = __builtin_amdgcn_mfma_scale_f32_32x32x64_f8f6f4(            \
        dup4(CA[2]), dup4(CB[0]), acc[2][0], 4, 4, 0, 127, 0, 127);         \
    acc[2][1] = __builtin_amdgcn_mfma_scale_f32_32x32x64_f8f6f4(            \
        dup4(CA[2]), dup4(CB[1]), acc[2][1], 4, 4, 0, 127, 0, 127);         \
    acc[3][0] = __builtin_amdgcn_mfma_scale_f32_32x32x64_f8f6f4(            \
        dup4(CA[3]), dup4(CB[0]), acc[3][0], 4, 4, 0, 127, 0, 127);         \
    acc[3][1] = __builtin_amdgcn_mfma_scale_f32_32x32x64_f8f6f4(            \
        dup4(CA[3]), dup4(CB[1]), acc[3][1], 4, 4, 0, 127, 0, 127);         \
    __builtin_amdgcn_s_setprio(0);

#define PREFETCH(KT, NA, NB)                                                \
    if ((KT) < 15) {                                                        \
        const char* An = As[((KT) + 1) & 3];                                \
        const char* Bn = Bs[((KT) + 1) & 3];                                \
        NA[0] = *(const i32x4*)(An + aOff);                                 \
        NA[1] = *(const i32x4*)(An + aOff + 512);                           \
        NA[2] = *(const i32x4*)(An + aOff + 1024);                          \
        NA[3] = *(const i32x4*)(An + aOff + 1536);                          \
        NB[0] = *(const i32x4*)(Bn + bOff);                                 \
        NB[1] = *(const i32x4*)(Bn + bOff + 512);                           \
    }

#define BODY(KT, CA, CB, NA, NB)                                            \
  {                                                                         \
    if ((KT) + 3 <= 15) { STAGE_A((KT) + 3); STAGE_B((KT) + 3); }           \
    if (roleA) {                                                            \
        PREFETCH(KT, NA, NB)                                                \
        MFMA8(CA, CB)                                                       \
    } else {                                                                \
        MFMA8(CA, CB)                                                       \
        PREFETCH(KT, NA, NB)                                                \
    }                                                                       \
    if ((KT) < 15) {                                                        \
        if ((KT) <= 12) { asm volatile("s_waitcnt vmcnt(2)" ::: "memory"); }\
        else            { asm volatile("s_waitcnt vmcnt(0)" ::: "memory"); }\
        __builtin_amdgcn_s_barrier();                                       \
        __builtin_amdgcn_sched_barrier(0);                                  \
    }                                                                       \
  }

    for (int kt2 = 0; kt2 < 8; ++kt2) {
        BODY(kt2 * 2,     fa0, fb0, fa1, fb1);
        BODY(kt2 * 2 + 1, fa1, fb1, fa0, fb0);
    }
#undef STAGE_A
#undef STAGE_B
#undef MFMA8
#undef PREFETCH
#undef BODY

    // Fused reduction per 64x64 (b,t) cell (r10-verified layout).
    // C/D: col = lane&31, row = (reg&3) + 8*(reg>>2) + 4*(lane>>5).
#pragma unroll
    for (int h = 0; h < 2; ++h) {
        float cm[2];
#pragma unroll
        for (int ni = 0; ni < 2; ++ni) {
            float m = acc[h * 2][ni][0];
#pragma unroll
            for (int dm = 0; dm < 2; ++dm)
#pragma unroll
                for (int r = 0; r < 16; ++r)
                    m = fmaxf(m, acc[h * 2 + dm][ni][r]);
            m = fmaxf(m, __shfl_xor(m, 32));   // other 16 rows of the 32-row tile
            cm[ni] = m;                        // col max, replicated over lane>>5
        }
        float s = cm[0] + cm[1];
        s += __shfl_xor(s, 1);
        s += __shfl_xor(s, 2);
        s += __shfl_xor(s, 4);
        s += __shfl_xor(s, 8);
        s += __shfl_xor(s, 16);
        if (lane == 0) {
            int b = tm * 4 + wr * 2 + h;
            int t = tn * 4 + wc;
            aggr[b * 128 + t] = s;
        }
    }
}

// ---------------------------------------------------------------------------
// Parallel loss: stage 1 = one block per x (128 threads over y), stage 2 = sum.
__global__ void loss_stage1(const float* __restrict__ aggr, float* __restrict__ red)
{
    const int x = blockIdx.x;
    const int y = threadIdx.x;
    const float diag = aggr[x * 129];
    float ms = 0.f, mi = 0.f;
    if (y != x) {
        ms = fmaxf(0.2f + aggr[x * 128 + y] - diag, 0.f);
        mi = fmaxf(0.2f + aggr[y * 128 + x] - diag, 0.f);
    }
#pragma unroll
    for (int o = 32; o; o >>= 1) {
        ms = fmaxf(ms, __shfl_xor(ms, o));
        mi = fmaxf(mi, __shfl_xor(mi, o));
    }
    __shared__ float sm[2], si[2];
    if ((y & 63) == 0) { sm[y >> 6] = ms; si[y >> 6] = mi; }
    __syncthreads();
    if (y == 0) red[x] = fmaxf(sm[0], sm[1]) + fmaxf(si[0], si[1]);
}

__global__ void loss_stage2(const float* __restrict__ red, float* __restrict__ out)
{
    float v = red[threadIdx.x];
#pragma unroll
    for (int o = 32; o; o >>= 1) v += __shfl_xor(v, o);
    __shared__ float s[2];
    if ((threadIdx.x & 63) == 0) s[threadIdx.x >> 6] = v;
    __syncthreads();
    if (threadIdx.x == 0) *out = s[0] + s[1];
}

// ---------------------------------------------------------------------------
extern "C" void kernel_launch(void* const* d_in, const int* in_sizes, int n_in,
                              void* d_out, int out_size, void* d_ws, size_t ws_size,
                              hipStream_t stream)
{
    const float* im_set = (const float*)d_in[0];
    const float* s_seq  = (const float*)d_in[1];
    const int*   im_len = (const int*)d_in[2];
    const int*   s_len  = (const int*)d_in[3];
    float* out = (float*)d_out;

    unsigned char* Abf = (unsigned char*)d_ws;                          // 4 MiB
    unsigned char* Bbf = (unsigned char*)d_ws + (4u << 20);             // 4 MiB
    float*         agg = (float*)((char*)d_ws + (8u << 20));            // 64 KiB
    float*         red = (float*)((char*)d_ws + (8u << 20) + 65536);    // 512 B

    conv_kernel<<<8192, 256, 0, stream>>>(im_set, im_len, s_seq, s_len,
                                          (unsigned*)Abf, (unsigned*)Bbf);

    gemm_aggr_kernel<<<dim3(32, 32), 512, 0, stream>>>(Abf, Bbf, agg);

    loss_stage1<<<128, 128, 0, stream>>>(agg, red);
    loss_stage2<<<1, 128, 0, stream>>>(red, out);
}

// Round 20
// 53.038 us; speedup vs baseline: 1.5227x; 1.0370x over previous
//
#include <hip/hip_runtime.h>

typedef __attribute__((ext_vector_type(4))) int   i32x4;
typedef __attribute__((ext_vector_type(8))) int   i32x8;
typedef __attribute__((ext_vector_type(16))) float f32x16;

// ---------------------------------------------------------------------------
// f32 -> fp4 e2m1 (nearest), values {0,.5,1,1.5,2,3,4,6} with sign.
__device__ __forceinline__ unsigned enc4(float v) {
    unsigned s = (__float_as_uint(v) >> 31) << 3;
    float a = fabsf(v);
    unsigned c = a < 0.25f ? 0u : a < 0.75f ? 1u : a < 1.25f ? 2u : a < 1.75f ? 3u
               : a < 2.5f  ? 4u : a < 3.5f  ? 5u : a < 5.0f  ? 6u : 7u;
    return s | c;
}

// Fused slice + convert(f32 -> packed fp4 e2m1) + mask-zero, writing the
// operands PRE-TILED in GEMM LDS-slot order (r18-verified):
//   dword addr = panel(m>>8)*32768 + kt(c>>6)*2048 + h((c>>5)&1)*1024
//              + row(m&255)*4 + q((c>>3)&3)
__global__ void conv_kernel(const float* __restrict__ im, const int* __restrict__ iml,
                            const float* __restrict__ ss, const int* __restrict__ sl,
                            unsigned* __restrict__ Ad, unsigned* __restrict__ Bd)
{
    int bid = blockIdx.x;
    const float* src; const int* len; unsigned* dst; int rawL, adj;
    if (bid < 4096) { src = im; len = iml; dst = Ad; rawL = 65; adj = -1; }
    else { bid -= 4096; src = ss; len = sl; dst = Bd; rawL = 67; adj = -3; }
    int t = threadIdx.x;
    int m = bid * 2 + (t >> 7);        // output row 0..8191
    int c = (t & 127) * 8;             // elem offset within row
    int b = m >> 6;
    int i = m & 63;
    int lim = len[b] + adj;
    float4 v0 = make_float4(0.f, 0.f, 0.f, 0.f), v1 = v0;
    if (i < lim) {
        const float* p = src + ((size_t)(b * rawL + 1 + i) << 10) + c;
        v0 = *(const float4*)p;
        v1 = *(const float4*)(p + 4);
    }
    unsigned w = enc4(v0.x) | (enc4(v0.y) << 4) | (enc4(v0.z) << 8)  | (enc4(v0.w) << 12)
               | (enc4(v1.x) << 16) | (enc4(v1.y) << 20) | (enc4(v1.z) << 24) | (enc4(v1.w) << 28);
    dst[(m >> 8) * 32768 + (c >> 6) * 2048 + ((c >> 5) & 1) * 1024
        + (m & 255) * 4 + ((c >> 3) & 3)] = w;
}

// ---------------------------------------------------------------------------
__device__ __forceinline__ void gload_lds16(const void* g, void* l) {
    __builtin_amdgcn_global_load_lds((const __attribute__((address_space(1))) void*)g,
                                     (__attribute__((address_space(3))) void*)l,
                                     16, 0, 0);
}

__device__ __forceinline__ i32x8 dup4(i32x4 a) {
    return __builtin_shufflevector(a, a, 0, 1, 2, 3, 0, 1, 2, 3);
}

// 256x256 tile, BK=64 (fp4), 8 waves (2M x 4N), per-wave 128x64.
// Pre-tiled operands (r18: 0 bank conflicts, contiguous 8KB gload staging).
// NEW (r20): 2 K-TILES PER BODY -> one {vmcnt(0); s_barrier} per 2 k-tiles
// (sync was ~23% of the serial body budget; overlap attempts r5-r19 all
// null, so shrink the terms instead). Ring-3 of 16KB slot-pairs (96 KiB).
// Body j: [gate][stage(j+2): tiles 2j+4,2j+5][read ktile 2j+1 -> setO]
//         [MFMA ktile 2j (setE)][read ktile 2j+2 -> setE][MFMA 2j+1 (setO)]
// Hazards verified: entry vmcnt(0) drains stage(j+1) (1 body ~3300cyc old,
// L2-resident -> free) covering both in-body reads; stage(j+2) overwrites
// pair (j-1)%3 last read in body j-1 (before this barrier) -> WAR-safe;
// MFMA(2j+1) is >=1 MFMA-block (~280cyc) after its reads -> lgkm covered.
// MFMA: mfma_scale_f32_32x32x64_f8f6f4, cbsz=blgp=4 (fp4), scale=1 (E8M0 127).
// C/D (r10-verified): col=lane&31, row=(reg&3)+8*(reg>>2)+4*(lane>>5).
__global__ void __launch_bounds__(512) gemm_aggr_kernel(const unsigned char* __restrict__ A,
                                                        const unsigned char* __restrict__ B,
                                                        float* __restrict__ aggr)
{
    __shared__ __align__(16) char As[3][16384];   // slot-pair: 2 tiles x 8KB
    __shared__ __align__(16) char Bs[3][16384];

    const int tid  = threadIdx.x;
    const int lane = tid & 63;
    const int wid  = tid >> 6;        // 0..7
    const int wr   = wid >> 2;        // 0..1 : 128-row half of BM=256
    const int wc   = wid & 3;         // 0..3 : 64-col quarter of BN=256
    const int tm   = blockIdx.y;      // 0..31
    const int tn   = blockIdx.x;      // 0..31

    const int r31 = lane & 31;
    const int g2  = lane >> 5;        // 0..1

    // Staging: panel base + ktile*8192 + tid*16 -- contiguous 8KB per tile.
    const unsigned char* gA_t = A + (size_t)tm * 131072 + tid * 16;
    const unsigned char* gB_t = B + (size_t)tn * 131072 + tid * 16;

    // stage body-pair j: tiles 2j, 2j+1 -> slot pair j%3 (4 gloads)
#define STAGE(j)                                                              \
    gload_lds16(gA_t + (2*(j))   * 8192, As[(j) % 3]        + tid * 16);      \
    gload_lds16(gA_t + (2*(j)+1) * 8192, As[(j) % 3] + 8192 + tid * 16);      \
    gload_lds16(gB_t + (2*(j))   * 8192, Bs[(j) % 3]        + tid * 16);      \
    gload_lds16(gB_t + (2*(j)+1) * 8192, Bs[(j) % 3] + 8192 + tid * 16);

    f32x16 acc[4][2];   // [32-row block mi][32-col block ni]
#pragma unroll
    for (int mi = 0; mi < 4; ++mi)
#pragma unroll
        for (int ni = 0; ni < 2; ++ni)
#pragma unroll
            for (int r = 0; r < 16; ++r)
                acc[mi][ni][r] = 0.f;

    // Fragment byte offsets within an 8KB tile: g2*4096 + row*16.
    const int aOff = g2 * 4096 + (wr * 128 + r31) * 16;   // + mi*512
    const int bOff = g2 * 4096 + (wc * 64 + r31) * 16;    // + ni*512

    i32x4 faE[4], fbE[2], faO[4], fbO[2];   // E = even ktiles, O = odd

#define READF(FA, FB, Ab, Bb)                                               \
    FA[0] = *(const i32x4*)((Ab) + aOff);                                   \
    FA[1] = *(const i32x4*)((Ab) + aOff + 512);                             \
    FA[2] = *(const i32x4*)((Ab) + aOff + 1024);                            \
    FA[3] = *(const i32x4*)((Ab) + aOff + 1536);                            \
    FB[0] = *(const i32x4*)((Bb) + bOff);                                   \
    FB[1] = *(const i32x4*)((Bb) + bOff + 512);

    // Prologue: stage pairs 0,1; wait pair 0; read ktile 0 -> setE.
    STAGE(0)
    STAGE(1)
    asm volatile("s_waitcnt vmcnt(4)" ::: "memory");   // pair 0 landed
    __builtin_amdgcn_s_barrier();
    __builtin_amdgcn_sched_barrier(0);
    READF(faE, fbE, As[0], Bs[0])

#define MFMA8(CA, CB)                                                       \
    __builtin_amdgcn_s_setprio(1);                                          \
    acc[0][0] = __builtin_amdgcn_mfma_scale_f32_32x32x64_f8f6f4(            \
        dup4(CA[0]), dup4(CB[0]), acc[0][0], 4, 4, 0, 127, 0, 127);         \
    acc[0][1] = __builtin_amdgcn_mfma_scale_f32_32x32x64_f8f6f4(            \
        dup4(CA[0]), dup4(CB[1]), acc[0][1], 4, 4, 0, 127, 0, 127);         \
    acc[1][0] = __builtin_amdgcn_mfma_scale_f32_32x32x64_f8f6f4(            \
        dup4(CA[1]), dup4(CB[0]), acc[1][0], 4, 4, 0, 127, 0, 127);         \
    acc[1][1] = __builtin_amdgcn_mfma_scale_f32_32x32x64_f8f6f4(            \
        dup4(CA[1]), dup4(CB[1]), acc[1][1], 4, 4, 0, 127, 0, 127);         \
    acc[2][0] = __builtin_amdgcn_mfma_scale_f32_32x32x64_f8f6f4(            \
        dup4(CA[2]), dup4(CB[0]), acc[2][0], 4, 4, 0, 127, 0, 127);         \
    acc[2][1] = __builtin_amdgcn_mfma_scale_f32_32x32x64_f8f6f4(            \
        dup4(CA[2]), dup4(CB[1]), acc[2][1], 4, 4, 0, 127, 0, 127);         \
    acc[3][0] = __builtin_amdgcn_mfma_scale_f32_32x32x64_f8f6f4(            \
        dup4(CA[3]), dup4(CB[0]), acc[3][0], 4, 4, 0, 127, 0, 127);         \
    acc[3][1] = __builtin_amdgcn_mfma_scale_f32_32x32x64_f8f6f4(            \
        dup4(CA[3]), dup4(CB[1]), acc[3][1], 4, 4, 0, 127, 0, 127);         \
    __builtin_amdgcn_s_setprio(0);

#define BODY(J)                                                             \
  {                                                                         \
    asm volatile("s_waitcnt vmcnt(0)" ::: "memory");                        \
    __builtin_amdgcn_s_barrier();                                           \
    __builtin_amdgcn_sched_barrier(0);                                      \
    if ((J) + 2 <= 7) { STAGE((J) + 2) }                                    \
    READF(faO, fbO, As[(J) % 3] + 8192, Bs[(J) % 3] + 8192)  /* kt 2J+1 */  \
    MFMA8(faE, fbE)                                          /* kt 2J   */  \
    if ((J) < 7) {                                                          \
        READF(faE, fbE, As[((J) + 1) % 3], Bs[((J) + 1) % 3]) /* 2J+2 */    \
    }                                                                       \
    MFMA8(faO, fbO)                                          /* kt 2J+1 */  \
  }

    BODY(0) BODY(1) BODY(2) BODY(3) BODY(4) BODY(5) BODY(6) BODY(7)
#undef STAGE
#undef READF
#undef MFMA8
#undef BODY

    // Fused reduction per 64x64 (b,t) cell (r10-verified layout).
    // C/D: col = lane&31, row = (reg&3) + 8*(reg>>2) + 4*(lane>>5).
#pragma unroll
    for (int h = 0; h < 2; ++h) {
        float cm[2];
#pragma unroll
        for (int ni = 0; ni < 2; ++ni) {
            float m = acc[h * 2][ni][0];
#pragma unroll
            for (int dm = 0; dm < 2; ++dm)
#pragma unroll
                for (int r = 0; r < 16; ++r)
                    m = fmaxf(m, acc[h * 2 + dm][ni][r]);
            m = fmaxf(m, __shfl_xor(m, 32));   // other 16 rows of the 32-row tile
            cm[ni] = m;                        // col max, replicated over lane>>5
        }
        float s = cm[0] + cm[1];
        s += __shfl_xor(s, 1);
        s += __shfl_xor(s, 2);
        s += __shfl_xor(s, 4);
        s += __shfl_xor(s, 8);
        s += __shfl_xor(s, 16);
        if (lane == 0) {
            int b = tm * 4 + wr * 2 + h;
            int t = tn * 4 + wc;
            aggr[b * 128 + t] = s;
        }
    }
}

// ---------------------------------------------------------------------------
// Parallel loss: stage 1 = one block per x (128 threads over y), stage 2 = sum.
__global__ void loss_stage1(const float* __restrict__ aggr, float* __restrict__ red)
{
    const int x = blockIdx.x;
    const int y = threadIdx.x;
    const float diag = aggr[x * 129];
    float ms = 0.f, mi = 0.f;
    if (y != x) {
        ms = fmaxf(0.2f + aggr[x * 128 + y] - diag, 0.f);
        mi = fmaxf(0.2f + aggr[y * 128 + x] - diag, 0.f);
    }
#pragma unroll
    for (int o = 32; o; o >>= 1) {
        ms = fmaxf(ms, __shfl_xor(ms, o));
        mi = fmaxf(mi, __shfl_xor(mi, o));
    }
    __shared__ float sm[2], si[2];
    if ((y & 63) == 0) { sm[y >> 6] = ms; si[y >> 6] = mi; }
    __syncthreads();
    if (y == 0) red[x] = fmaxf(sm[0], sm[1]) + fmaxf(si[0], si[1]);
}

__global__ void loss_stage2(const float* __restrict__ red, float* __restrict__ out)
{
    float v = red[threadIdx.x];
#pragma unroll
    for (int o = 32; o; o >>= 1) v += __shfl_xor(v, o);
    __shared__ float s[2];
    if ((threadIdx.x & 63) == 0) s[threadIdx.x >> 6] = v;
    __syncthreads();
    if (threadIdx.x == 0) *out = s[0] + s[1];
}

// ---------------------------------------------------------------------------
extern "C" void kernel_launch(void* const* d_in, const int* in_sizes, int n_in,
                              void* d_out, int out_size, void* d_ws, size_t ws_size,
                              hipStream_t stream)
{
    const float* im_set = (const float*)d_in[0];
    const float* s_seq  = (const float*)d_in[1];
    const int*   im_len = (const int*)d_in[2];
    const int*   s_len  = (const int*)d_in[3];
    float* out = (float*)d_out;

    unsigned char* Abf = (unsigned char*)d_ws;                          // 4 MiB
    unsigned char* Bbf = (unsigned char*)d_ws + (4u << 20);             // 4 MiB
    float*         agg = (float*)((char*)d_ws + (8u << 20));            // 64 KiB
    float*         red = (float*)((char*)d_ws + (8u << 20) + 65536);    // 512 B

    conv_kernel<<<8192, 256, 0, stream>>>(im_set, im_len, s_seq, s_len,
                                          (unsigned*)Abf, (unsigned*)Bbf);

    gemm_aggr_kernel<<<dim3(32, 32), 512, 0, stream>>>(Abf, Bbf, agg);

    loss_stage1<<<128, 128, 0, stream>>>(agg, red);
    loss_stage2<<<1, 128, 0, stream>>>(red, out);
}